// Round 9
// baseline (1674.832 us; speedup 1.0000x reference)
//
#include <hip/hip_runtime.h>
#include <hip/hip_bf16.h>

#define S_LEN 2048
#define DH    128
#define NBH   32
#define KPAD  136         // Ks row pitch in halves (272B, multiple of 16B -> b128 ops stay b128)
#define VPAD  72          // Vt row pitch in halves (144B)

typedef __attribute__((ext_vector_type(4))) float    f32x4;
typedef __attribute__((ext_vector_type(8))) _Float16 h16x8;
typedef __attribute__((ext_vector_type(4))) _Float16 h16x4;
typedef __attribute__((ext_vector_type(2))) __fp16   fp16x2;

#if __has_builtin(__builtin_amdgcn_exp2f)
#define EXP2(x) __builtin_amdgcn_exp2f(x)
#else
#define EXP2(x) exp2f(x)
#endif

static __device__ __forceinline__ unsigned pk2(float lo, float hi) {
  union { fp16x2 h; unsigned u; } u;
  u.h = __builtin_amdgcn_cvt_pkrtz(lo, hi);
  return u.u;
}

// ROUND-0 structure (verified 242.7us, spill-free, 128 VGPR) + setprio (r8,
// harmless) + T13 defer-max (THIS ROUND'S ISOLATED CHANGE).
// Block = two 64-row q-strips (jq and 31-jq) of one (b,h), ONE k-sweep.
// XCD swizzle: flat%8 == bh%8 -> all 16 blocks of a (b,h) on one XCD.
// Complementary pairing: CU slots m and m+32 get jq and 15-jq -> 49 iters/CU.
// Double-buffered LDS: ONE barrier per k-iteration.
//
// T13 defer-max: when __all(mt <= m_run + 8) keep the old running max ->
// skip the 4 serial aO shuffles (~240cy cross-lane latency) + 32-FMA
// O-rescale per softmax_pack (x2 strips/iter).  P bounded by 2^8 in fp16
// (max 65504) - relative precision unchanged; round-1 ran this branch with
// bit-identical absmax.  Wave-uniform branch (no divergence).
__global__ __launch_bounds__(256, 2)
void attn_fwd(const float* __restrict__ Q, const float* __restrict__ K,
              const float* __restrict__ V, const float* __restrict__ scale,
              float* __restrict__ O) {
  __shared__ short Ks[2][64 * KPAD];
  __shared__ short Vt[2][128 * VPAD];

  const int tid  = threadIdx.x;
  const int w    = tid >> 6;
  const int lane = tid & 63;
  const int quad = lane >> 4;
  const int l16  = lane & 15;

  const int flat = (int)blockIdx.x;
  const int m_   = flat >> 3;
  const int jqi  = m_ & 15;
  const int bhh  = m_ >> 4;                       // 0..3
  const int jq   = (bhh & 2) ? (15 - jqi) : jqi;  // complement on second CU slot
  const int bh   = (flat & 7) | (bhh << 3);

  const size_t base = (size_t)bh * (S_LEN * DH);
  const float sc = scale[0] * 1.44269504088896340736f;  // fold log2(e)

  const int krow = tid >> 2, kcolf = (tid & 3) * 32;    // K staging: 4 thr/row
  const int vd = (tid & 31) * 4, vkb = (tid >> 5) * 4;  // V staging: 4k x 4d transpose

  int vrow[8], voff[8];
#pragma unroll
  for (int dt = 0; dt < 8; ++dt) {
    const int row = dt * 16 + l16;
    const int mm = (row ^ (row >> 4)) & 14;
    vrow[dt] = row * VPAD;
    voff[dt] = ((quad * 2) ^ mm) << 2;
  }

  const int q0A = jq * 64;
  const int q0B = (31 - jq) * 64;
  const int nkt = 32 - jq;
  const int qrowA = q0A + w * 16 + l16;
  const int qrowB = q0B + w * 16 + l16;

  h16x8 qfA[4], qfB[4];
  {
    const float* qpA = Q + base + (size_t)qrowA * DH + quad * 8;
    const float* qpB = Q + base + (size_t)qrowB * DH + quad * 8;
#pragma unroll
    for (int f = 0; f < 4; ++f) {
      f32x4 a = *(const f32x4*)(qpA + f * 32);
      f32x4 b = *(const f32x4*)(qpA + f * 32 + 4);
      union { h16x8 v; unsigned u[4]; } t;
      t.u[0] = pk2(a[0] * sc, a[1] * sc);
      t.u[1] = pk2(a[2] * sc, a[3] * sc);
      t.u[2] = pk2(b[0] * sc, b[1] * sc);
      t.u[3] = pk2(b[2] * sc, b[3] * sc);
      qfA[f] = t.v;
      a = *(const f32x4*)(qpB + f * 32);
      b = *(const f32x4*)(qpB + f * 32 + 4);
      t.u[0] = pk2(a[0] * sc, a[1] * sc);
      t.u[1] = pk2(a[2] * sc, a[3] * sc);
      t.u[2] = pk2(b[0] * sc, b[1] * sc);
      t.u[3] = pk2(b[2] * sc, b[3] * sc);
      qfB[f] = t.v;
    }
  }

  f32x4 OA[8], OB[8];
#pragma unroll
  for (int i = 0; i < 8; ++i) { OA[i] = (f32x4){0.f,0.f,0.f,0.f}; OB[i] = (f32x4){0.f,0.f,0.f,0.f}; }
  float mA = -1e30f, lA = 0.f, mB = -1e30f, lB = 0.f;

  auto softmax_pack = [&](f32x4* st, float& m_run, float& l_run, f32x4* Oacc, int* pd) {
    float mt = st[0][0];
#pragma unroll
    for (int t = 0; t < 4; ++t)
#pragma unroll
      for (int r = 0; r < 4; ++r) mt = fmaxf(mt, st[t][r]);
    mt = fmaxf(mt, __shfl_xor(mt, 16));
    mt = fmaxf(mt, __shfl_xor(mt, 32));
    // T13 defer-max: skip O-rescale while tile max hasn't outgrown m_run+8
    const bool defer = __all(mt <= m_run + 8.0f) != 0;
    const float m_new = defer ? m_run : fmaxf(m_run, mt);
    float p[16], rs = 0.f;
#pragma unroll
    for (int t = 0; t < 4; ++t)
#pragma unroll
      for (int r = 0; r < 4; ++r) { p[t*4+r] = EXP2(st[t][r] - m_new); rs += p[t*4+r]; }
    rs += __shfl_xor(rs, 16);
    rs += __shfl_xor(rs, 32);
    if (defer) {
      l_run += rs;
    } else {
      const float alpha = EXP2(m_run - m_new);
      l_run = l_run * alpha + rs;
      m_run = m_new;
      float aO[4];
#pragma unroll
      for (int r = 0; r < 4; ++r) aO[r] = __shfl(alpha, quad * 4 + r);
#pragma unroll
      for (int dt = 0; dt < 8; ++dt)
#pragma unroll
        for (int r = 0; r < 4; ++r) Oacc[dt][r] *= aO[r];
    }
#pragma unroll
    for (int t = 0; t < 4; ++t) {
      pd[t*2]   = (int)pk2(p[t*4+0], p[t*4+1]);
      pd[t*2+1] = (int)pk2(p[t*4+2], p[t*4+3]);
    }
  };

  f32x4 ka[8], va[8];
  auto load_tile = [&](int k0) {
    const float* kp = K + base + (size_t)(k0 + krow) * DH + kcolf;
#pragma unroll
    for (int q = 0; q < 8; ++q) ka[q] = *(const f32x4*)(kp + q * 4);
#pragma unroll
    for (int kk = 0; kk < 2; ++kk) {
      const float* vp = V + base + (size_t)(k0 + vkb + kk * 32) * DH + vd;
#pragma unroll
      for (int i = 0; i < 4; ++i) va[kk*4+i] = *(const f32x4*)(vp + i * DH);
    }
  };
  auto write_tile = [&](int buf) {
    short* ksw = Ks[buf];
    short* vtw = Vt[buf];
#pragma unroll
    for (int q2 = 0; q2 < 4; ++q2) {
      f32x4 a = ka[2*q2], b = ka[2*q2+1];
      union { h16x8 v; unsigned u[4]; } t;
      t.u[0] = pk2(a[0], a[1]); t.u[1] = pk2(a[2], a[3]);
      t.u[2] = pk2(b[0], b[1]); t.u[3] = pk2(b[2], b[3]);
      *(h16x8*)&ksw[krow * KPAD + kcolf + q2 * 8] = t.v;
    }
#pragma unroll
    for (int kk = 0; kk < 2; ++kk) {
      const int c = (vkb + kk * 32) >> 2;
#pragma unroll
      for (int j = 0; j < 4; ++j) {
        const int row = vd + j;
        const int mm = (row ^ (row >> 4)) & 14;
        union { h16x4 v; unsigned u[2]; } t;
        t.u[0] = pk2(va[kk*4+0][j], va[kk*4+1][j]);
        t.u[1] = pk2(va[kk*4+2][j], va[kk*4+3][j]);
        *(h16x4*)&vtw[row * VPAD + ((c ^ mm) << 2)] = t.v;
      }
    }
  };

  // prologue: tile 0 -> buf 0
  load_tile(0);
  write_tile(0);
  __syncthreads();

#pragma unroll 1
  for (int kt = 0; kt < nkt; ++kt) {
    const int k0 = kt * 64;
    const int buf = kt & 1;
    const bool more = (kt + 1 < nkt);

    if (more) load_tile(k0 + 64);   // in flight across compute

    const bool actA = (kt <= jq);
    const bool diagA = (kt == jq);
    const bool diagB = (kt == nkt - 1);
    const short* ksb = Ks[buf];
    const short* vtb = Vt[buf];

    // ---- S^T = K * Qs^T (K-fragments shared between strips) ----
    f32x4 stA[4], stB[4];
#pragma unroll
    for (int t = 0; t < 4; ++t) { stA[t] = (f32x4){0.f,0.f,0.f,0.f}; stB[t] = (f32x4){0.f,0.f,0.f,0.f}; }
    __builtin_amdgcn_s_setprio(1);
#pragma unroll
    for (int t = 0; t < 4; ++t) {
      const bool needB = !diagB || (t <= w);          // skip fully-masked diag tiles
      const bool needA = actA && (!diagA || (t <= w));
      if (needB || needA) {
#pragma unroll
        for (int f = 0; f < 4; ++f) {
          h16x8 kf = *(const h16x8*)&ksb[(t * 16 + l16) * KPAD + f * 32 + quad * 8];
          if (needB) stB[t] = __builtin_amdgcn_mfma_f32_16x16x32_f16(kf, qfB[f], stB[t], 0, 0, 0);
          if (needA) stA[t] = __builtin_amdgcn_mfma_f32_16x16x32_f16(kf, qfA[f], stA[t], 0, 0, 0);
        }
      }
    }
    __builtin_amdgcn_s_setprio(0);

    // ---- causal masks (diagonal tiles only) ----
    if (diagB) {
#pragma unroll
      for (int t = 0; t < 4; ++t)
#pragma unroll
        for (int r = 0; r < 4; ++r)
          if (k0 + t * 16 + quad * 4 + r > qrowB) stB[t][r] = -1e30f;
    }
    int pdA[8], pdB[8];
    softmax_pack(stB, mB, lB, OB, pdB);
    if (actA) {
      if (diagA) {
#pragma unroll
        for (int t = 0; t < 4; ++t)
#pragma unroll
          for (int r = 0; r < 4; ++r)
            if (k0 + t * 16 + quad * 4 + r > qrowA) stA[t][r] = -1e30f;
      }
      softmax_pack(stA, mA, lA, OA, pdA);
    }

    // ---- P transform (C->A layout) + O += P*V (V-fragments shared) ----
#pragma unroll
    for (int h = 0; h < 2; ++h) {
      union { h16x8 v; int u[4]; } paA, paB;
#pragma unroll
      for (int hp = 0; hp < 4; ++hp) {
        const int src = (2 * (quad & 1) + (hp >> 1)) * 16 + l16;
        int va_ = __shfl(pdB[4*h + (hp & 1)], src);
        int vb_ = __shfl(pdB[4*h + 2 + (hp & 1)], src);
        paB.u[hp] = (quad >= 2) ? vb_ : va_;
        if (actA) {
          va_ = __shfl(pdA[4*h + (hp & 1)], src);
          vb_ = __shfl(pdA[4*h + 2 + (hp & 1)], src);
          paA.u[hp] = (quad >= 2) ? vb_ : va_;
        }
      }
      __builtin_amdgcn_s_setprio(1);
#pragma unroll
      for (int dt = 0; dt < 8; ++dt) {
        const int off0 = vrow[dt] + (voff[dt] ^ (h << 5));
        h16x8 vf = *(const h16x8*)&vtb[off0];
        OB[dt] = __builtin_amdgcn_mfma_f32_16x16x32_f16(paB.v, vf, OB[dt], 0, 0, 0);
        if (actA) OA[dt] = __builtin_amdgcn_mfma_f32_16x16x32_f16(paA.v, vf, OA[dt], 0, 0, 0);
      }
      __builtin_amdgcn_s_setprio(0);
    }

    if (more) write_tile(buf ^ 1);  // next tile into other buffer
    __syncthreads();                // single barrier per iteration
  }

  // ---- epilogue ----
  auto store_o = [&](f32x4* Oacc, float l_run, int q0) {
    float lO[4];
#pragma unroll
    for (int r = 0; r < 4; ++r) lO[r] = 1.0f / __shfl(l_run, quad * 4 + r);
#pragma unroll
    for (int dt = 0; dt < 8; ++dt)
#pragma unroll
      for (int r = 0; r < 4; ++r) {
        const size_t row = q0 + w * 16 + quad * 4 + r;
        O[base + row * DH + dt * 16 + l16] = Oacc[dt][r] * lO[r];
      }
  };
  store_o(OB, lB, q0B);
  store_o(OA, lA, q0A);
}

extern "C" void kernel_launch(void* const* d_in, const int* in_sizes, int n_in,
                              void* d_out, int out_size, void* d_ws, size_t ws_size,
                              hipStream_t stream) {
  const float* Q  = (const float*)d_in[0];
  const float* K  = (const float*)d_in[1];
  const float* V  = (const float*)d_in[2];
  const float* sc = (const float*)d_in[3];
  float* O = (float*)d_out;
  attn_fwd<<<dim3(512), dim3(256), 0, stream>>>(Q, K, V, sc, O);
}